// Round 4
// baseline (143.139 us; speedup 1.0000x reference)
//
#include <hip/hip_runtime.h>

// PolynomialAttn: B=2,H=16,S=2048,D=64, degree=2, eps=1e-4, fp32 in/out.
// v13b: identical theory to v13 (round-2 submission); round-3 bench was an
// infra failure ("container failed twice"), so this is a re-run with one
// hardening tweak (no K-prefetch on the final tile).
// Theory recap: per-SIMD MFMA pipe time fixed at 8.2k cyc, VALU ~13.8k cyc
// (matches VALUBusy 37% : MfmaUtil 23%); occupancy/L2/staging changes all
// null => VALU is the largest reducible term.
//   (1) persistent opaque zero f32x16 as QK's C-input (kills 16 movs/tile),
//   (2) denominator via all-ones-A MFMA into oaccD (kills 8 pk_adds + shfl;
//       numerator and denominator share the same bf16-rounded x),
//   (3) s_setprio(1) around QK/PV MFMA clusters,
//   (4) launch_bounds(256,3) for register headroom.

#define S_LEN 2048
#define DH    64
#define BQ    64
#define BK    64
#define EPSTR 68        // epilogue fp32 stride
#define PSTR  65        // prepass V-transpose LDS stride
#define BH_N  32        // B*H
#define PER_BH (S_LEN * DH)   // 131072 elems
#define NT    (S_LEN / BK)    // 32 KV tiles

typedef __bf16 bf16x8 __attribute__((ext_vector_type(8)));
typedef __bf16 bf16x2 __attribute__((ext_vector_type(2)));
typedef float  f32x2  __attribute__((ext_vector_type(2)));
typedef float  f32x4  __attribute__((ext_vector_type(4)));
typedef float  f32x16 __attribute__((ext_vector_type(16)));
typedef unsigned int uivec2 __attribute__((ext_vector_type(2)));

__device__ __forceinline__ unsigned short f2bf(float f) {
    union { float f; unsigned int u; } x; x.f = f;
    unsigned int u = x.u;
    return (unsigned short)((u + 0x7fffu + ((u >> 16) & 1u)) >> 16);  // RNE
}

__device__ __forceinline__ unsigned int pack2bf(float lo, float hi) {
#if __has_builtin(__builtin_amdgcn_cvt_pk_bf16_f32)
    bf16x2 p = __builtin_amdgcn_cvt_pk_bf16_f32(lo, hi);
    union { bf16x2 v; unsigned int u; } c; c.v = p;
    return c.u;
#else
    return (unsigned int)f2bf(lo) | ((unsigned int)f2bf(hi) << 16);
#endif
}

__device__ __forceinline__ void pl32swap(unsigned int& a, unsigned int& b) {
#if __has_builtin(__builtin_amdgcn_permlane32_swap)
    uivec2 r = __builtin_amdgcn_permlane32_swap(a, b, false, false);
    a = r[0]; b = r[1];
#else
    asm("v_permlane32_swap_b32 %0, %1" : "+v"(a), "+v"(b));
#endif
}

// ---------------- prepass: K -> fragment-order bf16, V -> V^T fragment-order bf16 ----
// Kf layout (ushorts): [bh][t][e][ks][lane]*8 ; lane(l31,h) holds
//   K[bh][64t + 32e + l31][16ks + 8h + 0..7]
// Vf layout (ushorts): [bh][t][e][ksl][mt][lane]*8 ; lane(l31,h) holds
//   V^T[bh][mt*32 + l31][64t + 32e + 16ksl + 8h + 0..7]
__global__ __launch_bounds__(256)
void prepass_kernel(const float* __restrict__ kg, const float* __restrict__ vg,
                    unsigned short* __restrict__ kfo, unsigned short* __restrict__ vfo)
{
    __shared__ unsigned short Lk[64 * 72];
    __shared__ unsigned short Lv[64 * PSTR];
    const int tid = threadIdx.x;
    const int bh  = blockIdx.y;
    const int t   = blockIdx.x;
    const size_t base = (size_t)bh * PER_BH + (size_t)t * 64 * DH;

    const float4* kf4 = (const float4*)(kg + base);
    const float4* vf4 = (const float4*)(vg + base);
    #pragma unroll
    for (int r = 0; r < 4; ++r) {
        int idx = r * 256 + tid;              // float4 index in 64x64 tile
        int row = idx >> 4, c4 = idx & 15;
        float4 f = kf4[idx];
        ushort4 hh;
        hh.x = f2bf(f.x); hh.y = f2bf(f.y); hh.z = f2bf(f.z); hh.w = f2bf(f.w);
        *(ushort4*)&Lk[row * 72 + c4 * 4] = hh;
        float4 g = vf4[idx];
        unsigned short* pv = &Lv[row * PSTR + c4 * 4];
        pv[0] = f2bf(g.x); pv[1] = f2bf(g.y); pv[2] = f2bf(g.z); pv[3] = f2bf(g.w);
    }
    __syncthreads();

    unsigned short* kout = kfo + (size_t)bh * PER_BH + (size_t)t * 4096;
    #pragma unroll
    for (int r = 0; r < 2; ++r) {
        int pos = r * 256 + tid;
        int lam = pos & 63, rest = pos >> 6;
        int e = rest >> 2, ks = rest & 3;
        int l31 = lam & 31, h = lam >> 5;
        uint4 v = *(const uint4*)&Lk[(e * 32 + l31) * 72 + ks * 16 + h * 8];
        *(uint4*)(kout + (size_t)pos * 8) = v;
    }
    unsigned short* vout = vfo + (size_t)bh * PER_BH + (size_t)t * 4096;
    #pragma unroll
    for (int r = 0; r < 2; ++r) {
        int pos = r * 256 + tid;
        int lam = pos & 63, rest = pos >> 6;
        int e = rest >> 2, ksl = (rest >> 1) & 1, mt = rest & 1;
        int l31 = lam & 31, h = lam >> 5;
        int d  = mt * 32 + l31;
        int j0 = e * 32 + ksl * 16 + h * 8;
        union { unsigned short s[8]; uint4 u; } u;
        #pragma unroll
        for (int jj = 0; jj < 8; ++jj) u.s[jj] = Lv[(j0 + jj) * PSTR + d];
        *(uint4*)(vout + (size_t)pos * 8) = u.u;
    }
}

// ---------------- main kernel: register streams, VALU-lean transform ----------------
__global__ __launch_bounds__(256, 3)
void poly_attn_main(const float* __restrict__ qg,
                    const unsigned short* __restrict__ kfo,
                    const unsigned short* __restrict__ vfo,
                    float* __restrict__ og)
{
    __shared__ float epb[4 * 32 * EPSTR];   // per-wave O^T partials
    __shared__ float dbuf[128];             // per-wave denominator partials

    const int tid  = threadIdx.x;
    const int lane = tid & 63;
    const int w    = tid >> 6;
    const int sp   = w >> 1;      // strip: Q rows [32sp, 32sp+32)
    const int e    = w & 1;       // j-half of each KV tile
    const int l31  = lane & 31;
    const int h    = lane >> 5;

    // XCD swizzle: id%8 -> XCD; 4 bh per XCD (K+V 2MB working set in its L2)
    const int id = blockIdx.x;
    const int r5 = id & 31;
    const int bh = (r5 & 7) * 4 + (r5 >> 3);
    const int qt = id >> 5;                 // 0..31
    const int q0 = qt * BQ;

    const float* qb = qg + ((size_t)bh * S_LEN + q0) * DH;
    const unsigned short* kw = kfo + (size_t)bh * PER_BH + e * 2048 + (size_t)lane * 8;
    const unsigned short* vw = vfo + (size_t)bh * PER_BH + e * 2048 + (size_t)lane * 8;
    float* ob = og + ((size_t)bh * S_LEN + q0) * DH;

    // ---- Q B-fragments: rows 32sp + l31, cols 16ks + 8h + 0..7 ----
    bf16x8 qfrag[4];
    #pragma unroll
    for (int ks = 0; ks < 4; ++ks) {
        const float* qp = qb + (32 * sp + l31) * DH + ks * 16 + h * 8;
        float4 f0 = *(const float4*)qp;
        float4 f1 = *(const float4*)(qp + 4);
        union { unsigned int d[4]; bf16x8 v; } u;
        u.d[0] = pack2bf(f0.x, f0.y);
        u.d[1] = pack2bf(f0.z, f0.w);
        u.d[2] = pack2bf(f1.x, f1.y);
        u.d[3] = pack2bf(f1.z, f1.w);
        qfrag[ks] = u.v;
    }

    f32x16 oacc[2];   // [mt]: O^T[d=mt*32+(r&3)+8(r>>2)+4h][i=l31] j-half partial
    #pragma unroll
    for (int mt = 0; mt < 2; ++mt)
        #pragma unroll
        for (int r = 0; r < 16; ++r) oacc[mt][r] = 0.f;
    f32x16 oaccD;     // denom[q=l31] replicated x16 (ones-A MFMA accumulator)
    #pragma unroll
    for (int r = 0; r < 16; ++r) oaccD[r] = 0.f;

    // persistent zero C-operand (opaque so it isn't re-materialized per tile)
    f32x16 zacc;
    #pragma unroll
    for (int r = 0; r < 16; ++r) zacc[r] = 0.f;
    asm volatile("" : "+v"(zacc));

    // all-ones bf16 A-fragment for the denominator MFMA (opaque, hoisted)
    bf16x8 onesv;
    {
        union { unsigned int d[4]; bf16x8 v; } u;
        u.d[0] = 0x3f803f80u; u.d[1] = 0x3f803f80u;
        u.d[2] = 0x3f803f80u; u.d[3] = 0x3f803f80u;
        onesv = u.v;
    }
    asm volatile("" : "+v"(onesv));

    uint4 kbuf[2][4], vbuf[4];
    unsigned int bsv[2][4];   // [ksl][dword] transformed B-frags

    // prologue: K(0) -> kbuf[0]
    #pragma unroll
    for (int x = 0; x < 4; ++x) kbuf[0][x] = *(const uint4*)(kw + x * 512);

    // BODY(T, CUR, NXT, KPF): V(T)->vbuf; QK(T) from kbuf[CUR] (C=zacc);
    // if KPF, K(T+1)->kbuf[NXT]; XF; PV(T)+denom MFMA.
#define BODY(TT, CUR, NXT, KPF)                                                     \
    {                                                                               \
        {                                                                           \
            const unsigned short* vn_ = vw + (size_t)(TT) * 4096;                   \
            _Pragma("unroll")                                                       \
            for (int x = 0; x < 4; ++x) vbuf[x] = *(const uint4*)(vn_ + x * 512);   \
        }                                                                           \
        f32x16 acc;                                                                 \
        __builtin_amdgcn_s_setprio(1);                                              \
        {                                                                           \
            union { uint4 u; bf16x8 v; } kc;                                        \
            kc.u = kbuf[CUR][0];                                                    \
            acc = __builtin_amdgcn_mfma_f32_32x32x16_bf16(kc.v, qfrag[0], zacc, 0, 0, 0); \
            kc.u = kbuf[CUR][1];                                                    \
            acc = __builtin_amdgcn_mfma_f32_32x32x16_bf16(kc.v, qfrag[1], acc, 0, 0, 0); \
            kc.u = kbuf[CUR][2];                                                    \
            acc = __builtin_amdgcn_mfma_f32_32x32x16_bf16(kc.v, qfrag[2], acc, 0, 0, 0); \
            kc.u = kbuf[CUR][3];                                                    \
            acc = __builtin_amdgcn_mfma_f32_32x32x16_bf16(kc.v, qfrag[3], acc, 0, 0, 0); \
        }                                                                           \
        __builtin_amdgcn_s_setprio(0);                                              \
        if (KPF) {                                                                  \
            const unsigned short* kn_ = kw + (size_t)((TT) + 1) * 4096;             \
            _Pragma("unroll")                                                       \
            for (int x = 0; x < 4; ++x) kbuf[NXT][x] = *(const uint4*)(kn_ + x * 512); \
        }                                                                           \
        _Pragma("unroll")                                                           \
        for (int ksl = 0; ksl < 2; ++ksl) {                                         \
            f32x2 va, vb, vc, vd;                                                   \
            va[0] = acc[8*ksl+0]; va[1] = acc[8*ksl+1];                             \
            vb[0] = acc[8*ksl+2]; vb[1] = acc[8*ksl+3];                             \
            vc[0] = acc[8*ksl+4]; vc[1] = acc[8*ksl+5];                             \
            vd[0] = acc[8*ksl+6]; vd[1] = acc[8*ksl+7];                             \
            va = va * va; vb = vb * vb; vc = vc * vc; vd = vd * vd;                 \
            unsigned int a0 = pack2bf(va[0], va[1]);                                \
            unsigned int a1 = pack2bf(vb[0], vb[1]);                                \
            unsigned int b0 = pack2bf(vc[0], vc[1]);                                \
            unsigned int b1 = pack2bf(vd[0], vd[1]);                                \
            pl32swap(a0, b0);                                                       \
            pl32swap(a1, b1);                                                       \
            bsv[ksl][0] = a0; bsv[ksl][1] = a1;                                     \
            bsv[ksl][2] = b0; bsv[ksl][3] = b1;                                     \
        }                                                                           \
        __builtin_amdgcn_s_setprio(1);                                              \
        _Pragma("unroll")                                                           \
        for (int ksl = 0; ksl < 2; ++ksl) {                                         \
            union { unsigned int d[4]; bf16x8 v; } bu;                              \
            bu.d[0] = bsv[ksl][0]; bu.d[1] = bsv[ksl][1];                           \
            bu.d[2] = bsv[ksl][2]; bu.d[3] = bsv[ksl][3];                           \
            union { uint4 u; bf16x8 v; } vv;                                        \
            vv.u = vbuf[ksl * 2 + 0];                                               \
            oacc[0] = __builtin_amdgcn_mfma_f32_32x32x16_bf16(vv.v, bu.v, oacc[0], 0, 0, 0); \
            vv.u = vbuf[ksl * 2 + 1];                                               \
            oacc[1] = __builtin_amdgcn_mfma_f32_32x32x16_bf16(vv.v, bu.v, oacc[1], 0, 0, 0); \
            oaccD  = __builtin_amdgcn_mfma_f32_32x32x16_bf16(onesv, bu.v, oaccD, 0, 0, 0); \
        }                                                                           \
        __builtin_amdgcn_s_setprio(0);                                              \
    }

    for (int T = 0; T < NT - 2; T += 2) {
        BODY(T,     0, 1, 1);
        BODY(T + 1, 1, 0, 1);
    }
    BODY(NT - 2, 0, 1, 1);
    BODY(NT - 1, 1, 0, 0);
#undef BODY

    // ---- denominator partial: oaccD rows are all identical = denom[q=l31] ----
    const float wavetot = oaccD[0];

    // ---- epilogue: stash partials, combine wave-pair j-halves, store ----
    {
        float* ep = epb + (size_t)w * (32 * EPSTR);
        #pragma unroll
        for (int mt = 0; mt < 2; ++mt) {
            #pragma unroll
            for (int g = 0; g < 4; ++g) {
                f32x4 vv;
                vv[0] = oacc[mt][4*g+0];
                vv[1] = oacc[mt][4*g+1];
                vv[2] = oacc[mt][4*g+2];
                vv[3] = oacc[mt][4*g+3];
                // O[i=l31][d = mt*32 + 8g + 4h + 0..3]
                *(f32x4*)&ep[l31 * EPSTR + mt * 32 + 8 * g + 4 * h] = vv;
            }
        }
        if (h == 0) dbuf[w * 32 + l31] = wavetot;
    }
    __syncthreads();

    // wave w: output strip so = w>>1 (rows [32so,32so+32)), d-half ho = w&1
    const int so = w >> 1, ho = w & 1;
    const int lr = lane >> 1;
    const float den = dbuf[(2 * so + 0) * 32 + lr] + dbuf[(2 * so + 1) * 32 + lr];
    const float inv = 1.0f / fmaxf(den, 1e-4f);
    const float* ea = epb + (size_t)(2 * so + 0) * (32 * EPSTR) + lr * EPSTR;
    const float* eb = epb + (size_t)(2 * so + 1) * (32 * EPSTR) + lr * EPSTR;
    #pragma unroll
    for (int it = 0; it < 4; ++it) {
        int d0 = ho * 32 + (lane & 1) * 16 + it * 4;
        f32x4 a = *(const f32x4*)&ea[d0];
        f32x4 b = *(const f32x4*)&eb[d0];
        f32x4 sm;
        sm[0] = (a[0] + b[0]) * inv;
        sm[1] = (a[1] + b[1]) * inv;
        sm[2] = (a[2] + b[2]) * inv;
        sm[3] = (a[3] + b[3]) * inv;
        *(f32x4*)&ob[(32 * so + lr) * DH + d0] = sm;
    }
}

// ---------------- fallback (self-contained, used if ws too small) ----------------
#define LSTR 72
__global__ __launch_bounds__(256, 2)
void poly_attn_fallback(const float* __restrict__ qg, const float* __restrict__ kg,
                        const float* __restrict__ vg, float* __restrict__ og)
{
    __shared__ unsigned short Qs[64 * LSTR];
    __shared__ unsigned short Ksl[64 * LSTR];
    __shared__ unsigned short Vt[64 * LSTR];
    __shared__ unsigned short Xsl[64 * LSTR];

    const int tid  = threadIdx.x;
    const int lane = tid & 63;
    const int w    = tid >> 6;
    const int c    = lane & 15;
    const int quad = lane >> 4;
    const int i0   = w * 16;

    const int bh = blockIdx.y;
    const int q0 = blockIdx.x * 64;

    const float* qb = qg + ((size_t)bh * S_LEN + q0) * DH;
    const float* kb = kg + (size_t)bh * S_LEN * DH;
    const float* vb = vg + (size_t)bh * S_LEN * DH;
    float*       ob = og + ((size_t)bh * S_LEN + q0) * DH;

    {
        const float4* qf4 = (const float4*)qb;
        #pragma unroll
        for (int r = 0; r < 4; ++r) {
            int idx = r * 256 + tid;
            int row = idx >> 4, c4 = idx & 15;
            float4 f = qf4[idx];
            ushort4 hh;
            hh.x = f2bf(f.x); hh.y = f2bf(f.y); hh.z = f2bf(f.z); hh.w = f2bf(f.w);
            *(ushort4*)&Qs[row * LSTR + c4 * 4] = hh;
        }
    }

    f32x4 oacc[4];
    #pragma unroll
    for (int t = 0; t < 4; ++t) { oacc[t][0]=0.f; oacc[t][1]=0.f; oacc[t][2]=0.f; oacc[t][3]=0.f; }
    float dsum[4] = {0.f, 0.f, 0.f, 0.f};

    for (int t0 = 0; t0 < S_LEN; t0 += 64) {
        __syncthreads();
        {
            const float4* kf4 = (const float4*)(kb + (size_t)t0 * DH);
            const float4* vf4 = (const float4*)(vb + (size_t)t0 * DH);
            #pragma unroll
            for (int r = 0; r < 4; ++r) {
                int idx = r * 256 + tid;
                int row = idx >> 4, c4 = idx & 15;
                float4 f = kf4[idx];
                ushort4 hh;
                hh.x = f2bf(f.x); hh.y = f2bf(f.y); hh.z = f2bf(f.z); hh.w = f2bf(f.w);
                *(ushort4*)&Ksl[row * LSTR + c4 * 4] = hh;
                float4 g = vf4[idx];
                int d0 = c4 * 4;
                Vt[(d0 + 0) * LSTR + row] = f2bf(g.x);
                Vt[(d0 + 1) * LSTR + row] = f2bf(g.y);
                Vt[(d0 + 2) * LSTR + row] = f2bf(g.z);
                Vt[(d0 + 3) * LSTR + row] = f2bf(g.w);
            }
        }
        __syncthreads();

        f32x4 xacc[4];
        #pragma unroll
        for (int t = 0; t < 4; ++t) { xacc[t][0]=0.f; xacc[t][1]=0.f; xacc[t][2]=0.f; xacc[t][3]=0.f; }
        #pragma unroll
        for (int k0 = 0; k0 < 64; k0 += 32) {
            bf16x8 af = *(const bf16x8*)&Qs[(i0 + c) * LSTR + k0 + quad * 8];
            #pragma unroll
            for (int tn = 0; tn < 4; ++tn) {
                bf16x8 bfg = *(const bf16x8*)&Ksl[(tn * 16 + c) * LSTR + k0 + quad * 8];
                xacc[tn] = __builtin_amdgcn_mfma_f32_16x16x32_bf16(af, bfg, xacc[tn], 0, 0, 0);
            }
        }
        #pragma unroll
        for (int tn = 0; tn < 4; ++tn)
            #pragma unroll
            for (int r = 0; r < 4; ++r) {
                float xv = xacc[tn][r];
                float xs = xv * xv;
                dsum[r] += xs;
                Xsl[(i0 + quad * 4 + r) * LSTR + tn * 16 + c] = f2bf(xs);
            }
        __syncthreads();

        #pragma unroll
        for (int k0 = 0; k0 < 64; k0 += 32) {
            bf16x8 af = *(const bf16x8*)&Xsl[(i0 + c) * LSTR + k0 + quad * 8];
            #pragma unroll
            for (int tn = 0; tn < 4; ++tn) {
                bf16x8 bfg = *(const bf16x8*)&Vt[(tn * 16 + c) * LSTR + k0 + quad * 8];
                oacc[tn] = __builtin_amdgcn_mfma_f32_16x16x32_bf16(af, bfg, oacc[tn], 0, 0, 0);
            }
        }
    }

    #pragma unroll
    for (int r = 0; r < 4; ++r) {
        float s = dsum[r];
        s += __shfl_xor(s, 1);
        s += __shfl_xor(s, 2);
        s += __shfl_xor(s, 4);
        s += __shfl_xor(s, 8);
        dsum[r] = 1.0f / fmaxf(s, 1e-4f);
    }
    #pragma unroll
    for (int tn = 0; tn < 4; ++tn)
        #pragma unroll
        for (int r = 0; r < 4; ++r)
            ob[(i0 + quad * 4 + r) * DH + tn * 16 + c] = oacc[tn][r] * dsum[r];
}

extern "C" void kernel_launch(void* const* d_in, const int* in_sizes, int n_in,
                              void* d_out, int out_size, void* d_ws, size_t ws_size,
                              hipStream_t stream) {
    (void)in_sizes; (void)n_in; (void)out_size;
    const float* q = (const float*)d_in[0];
    const float* k = (const float*)d_in[1];
    const float* v = (const float*)d_in[2];
    float* o = (float*)d_out;

    const size_t elems = (size_t)BH_N * PER_BH;              // 4,194,304
    const size_t need  = 2 * elems * sizeof(unsigned short); // 16.78 MB

    if (ws_size >= need) {
        unsigned short* kfo = (unsigned short*)d_ws;
        unsigned short* vfo = kfo + elems;
        prepass_kernel<<<dim3(NT, BH_N), 256, 0, stream>>>(k, v, kfo, vfo);
        poly_attn_main<<<dim3(BH_N * S_LEN / BQ), 256, 0, stream>>>(q, kfo, vfo, o);
    } else {
        poly_attn_fallback<<<dim3(S_LEN / 64, BH_N), 256, 0, stream>>>(q, k, v, o);
    }
}

// Round 5
// 137.184 us; speedup vs baseline: 1.0434x; 1.0434x over previous
//
#include <hip/hip_runtime.h>

// PolynomialAttn: B=2,H=16,S=2048,D=64, degree=2, eps=1e-4, fp32 in/out.
// v14: depth-4 DMA pipeline + 2-strip reuse.
// Corrected model (v13b counters): one 32x32x16 MFMA = ~32 SIMD-cycles;
// MfmaUtil 27.9% at 62us pins clock at 2.4GHz; VALUBusy includes MFMA, so
// true VALU is ~3% -- the SIMD idles ~70%. Invariant across v10-v13:
// per-wave per-tile period ~4.2-4.7k cyc vs 300-1200 busy => ~4k-cycle
// load-to-use latency under congestion; depth-1 prefetch (all prior
// versions) equilibrates at period ~= latency.
// v14: BQ=128 (4 waves, 2 Q-strips/wave: 16 MFMA per 8 staged fragments,
// half the stream traffic) + K/V staged once per block via global_load_lds
// into a 4-slot LDS ring (64KB, aliased with epilogue) with counted
// vmcnt(12): consumed tiles were issued 4 periods (~6k cyc) earlier.

#define S_LEN 2048
#define DH    64
#define BQ    128
#define BK    64
#define EPSTR 68        // epilogue fp32 stride
#define PSTR  65        // prepass V-transpose LDS stride
#define BH_N  32        // B*H
#define PER_BH (S_LEN * DH)   // 131072 elems
#define NT    (S_LEN / BK)    // 32 KV tiles
#define SLOT_BYTES 16384      // one KV tile: K 8KB + V 8KB
#define SMEM_BYTES 70656      // max(4*16KB ring, 69632B epilogue + 1KB dbuf)

typedef __bf16 bf16x8 __attribute__((ext_vector_type(8)));
typedef __bf16 bf16x2 __attribute__((ext_vector_type(2)));
typedef float  f32x2  __attribute__((ext_vector_type(2)));
typedef float  f32x4  __attribute__((ext_vector_type(4)));
typedef float  f32x16 __attribute__((ext_vector_type(16)));
typedef unsigned int uivec2 __attribute__((ext_vector_type(2)));

__device__ __forceinline__ unsigned short f2bf(float f) {
    union { float f; unsigned int u; } x; x.f = f;
    unsigned int u = x.u;
    return (unsigned short)((u + 0x7fffu + ((u >> 16) & 1u)) >> 16);  // RNE
}

__device__ __forceinline__ unsigned int pack2bf(float lo, float hi) {
#if __has_builtin(__builtin_amdgcn_cvt_pk_bf16_f32)
    bf16x2 p = __builtin_amdgcn_cvt_pk_bf16_f32(lo, hi);
    union { bf16x2 v; unsigned int u; } c; c.v = p;
    return c.u;
#else
    return (unsigned int)f2bf(lo) | ((unsigned int)f2bf(hi) << 16);
#endif
}

__device__ __forceinline__ void pl32swap(unsigned int& a, unsigned int& b) {
#if __has_builtin(__builtin_amdgcn_permlane32_swap)
    uivec2 r = __builtin_amdgcn_permlane32_swap(a, b, false, false);
    a = r[0]; b = r[1];
#else
    asm("v_permlane32_swap_b32 %0, %1" : "+v"(a), "+v"(b));
#endif
}

// DMA 16B/lane global->LDS (lds dest = uniform base + lane*16, linear).
__device__ __forceinline__ void dma16(const void* g, void* l) {
    __builtin_amdgcn_global_load_lds(
        (const __attribute__((address_space(1))) unsigned int*)g,
        (__attribute__((address_space(3))) unsigned int*)l, 16, 0, 0);
}

// ---------------- prepass: K -> fragment-order bf16, V -> V^T fragment-order bf16 ----
// Kf layout (ushorts): [bh][t][e][ks][lane]*8 ; lane(l31,h) holds
//   K[bh][64t + 32e + l31][16ks + 8h + 0..7]
// Vf layout (ushorts): [bh][t][e][ksl][mt][lane]*8 ; lane(l31,h) holds
//   V^T[bh][mt*32 + l31][64t + 32e + 16ksl + 8h + 0..7]
__global__ __launch_bounds__(256)
void prepass_kernel(const float* __restrict__ kg, const float* __restrict__ vg,
                    unsigned short* __restrict__ kfo, unsigned short* __restrict__ vfo)
{
    __shared__ unsigned short Lk[64 * 72];
    __shared__ unsigned short Lv[64 * PSTR];
    const int tid = threadIdx.x;
    const int bh  = blockIdx.y;
    const int t   = blockIdx.x;
    const size_t base = (size_t)bh * PER_BH + (size_t)t * 64 * DH;

    const float4* kf4 = (const float4*)(kg + base);
    const float4* vf4 = (const float4*)(vg + base);
    #pragma unroll
    for (int r = 0; r < 4; ++r) {
        int idx = r * 256 + tid;              // float4 index in 64x64 tile
        int row = idx >> 4, c4 = idx & 15;
        float4 f = kf4[idx];
        ushort4 hh;
        hh.x = f2bf(f.x); hh.y = f2bf(f.y); hh.z = f2bf(f.z); hh.w = f2bf(f.w);
        *(ushort4*)&Lk[row * 72 + c4 * 4] = hh;
        float4 g = vf4[idx];
        unsigned short* pv = &Lv[row * PSTR + c4 * 4];
        pv[0] = f2bf(g.x); pv[1] = f2bf(g.y); pv[2] = f2bf(g.z); pv[3] = f2bf(g.w);
    }
    __syncthreads();

    unsigned short* kout = kfo + (size_t)bh * PER_BH + (size_t)t * 4096;
    #pragma unroll
    for (int r = 0; r < 2; ++r) {
        int pos = r * 256 + tid;
        int lam = pos & 63, rest = pos >> 6;
        int e = rest >> 2, ks = rest & 3;
        int l31 = lam & 31, h = lam >> 5;
        uint4 v = *(const uint4*)&Lk[(e * 32 + l31) * 72 + ks * 16 + h * 8];
        *(uint4*)(kout + (size_t)pos * 8) = v;
    }
    unsigned short* vout = vfo + (size_t)bh * PER_BH + (size_t)t * 4096;
    #pragma unroll
    for (int r = 0; r < 2; ++r) {
        int pos = r * 256 + tid;
        int lam = pos & 63, rest = pos >> 6;
        int e = rest >> 2, ksl = (rest >> 1) & 1, mt = rest & 1;
        int l31 = lam & 31, h = lam >> 5;
        int d  = mt * 32 + l31;
        int j0 = e * 32 + ksl * 16 + h * 8;
        union { unsigned short s[8]; uint4 u; } u;
        #pragma unroll
        for (int jj = 0; jj < 8; ++jj) u.s[jj] = Lv[(j0 + jj) * PSTR + d];
        *(uint4*)(vout + (size_t)pos * 8) = u.u;
    }
}

// ---------------- main kernel: depth-4 DMA ring, 2 strips/wave -------------------
__global__ __launch_bounds__(256, 2)
void poly_attn_main(const float* __restrict__ qg,
                    const unsigned short* __restrict__ kfo,
                    const unsigned short* __restrict__ vfo,
                    float* __restrict__ og)
{
    __shared__ __align__(16) unsigned char smem[SMEM_BYTES];

    const int tid  = threadIdx.x;
    const int lane = tid & 63;
    const int w    = tid >> 6;
    const int p    = w >> 1;      // pair id: Q rows [64p, 64p+64)
    const int e    = w & 1;       // j-half of each KV tile
    const int l31  = lane & 31;
    const int h    = lane >> 5;

    // XCD swizzle: id%8 -> XCD; 4 bh per XCD (K+V 2MB working set in its L2)
    const int id = blockIdx.x;
    const int r5 = id & 31;
    const int bh = (r5 & 7) * 4 + (r5 >> 3);
    const int qt = id >> 5;                 // 0..15
    const int q0 = qt * BQ;

    const float* qb = qg + ((size_t)bh * S_LEN + q0) * DH;
    float* ob = og + ((size_t)bh * S_LEN + q0) * DH;

    // ---- Q B-fragments FIRST (so their loads fully drain before DMA issue) ----
    bf16x8 qfrag[2][4];
    #pragma unroll
    for (int s = 0; s < 2; ++s) {
        #pragma unroll
        for (int ks = 0; ks < 4; ++ks) {
            const float* qp = qb + (64 * p + 32 * s + l31) * DH + ks * 16 + h * 8;
            float4 f0 = *(const float4*)qp;
            float4 f1 = *(const float4*)(qp + 4);
            union { unsigned int d[4]; bf16x8 v; } u;
            u.d[0] = pack2bf(f0.x, f0.y);
            u.d[1] = pack2bf(f0.z, f0.w);
            u.d[2] = pack2bf(f1.x, f1.y);
            u.d[3] = pack2bf(f1.z, f1.w);
            qfrag[s][ks] = u.v;
        }
    }
    __builtin_amdgcn_sched_barrier(0);   // keep Q loads out of the DMA vmcnt stream

    // ---- per-wave DMA assignment: waves 0,1 stage K halves; 2,3 stage V halves ----
    const unsigned short* gw =
        ((w < 2) ? kfo : vfo) + (size_t)bh * PER_BH + (w & 1) * 2048 + (size_t)lane * 8;
    const int ldsoff = ((w < 2) ? 0 : 8192) + (w & 1) * 4096;

#define DMA_TILE(TT)                                                                \
    {                                                                               \
        const unsigned short* gs_ = gw + (size_t)(TT) * 4096;                       \
        unsigned char* lb_ = smem + ((TT) & 3) * SLOT_BYTES + ldsoff;               \
        dma16(gs_,        lb_);                                                     \
        dma16(gs_ + 512,  lb_ + 1024);                                              \
        dma16(gs_ + 1024, lb_ + 2048);                                              \
        dma16(gs_ + 1536, lb_ + 3072);                                              \
    }

    // prologue: fill the 4-deep ring (16 DMA instrs in flight per wave)
    DMA_TILE(0) DMA_TILE(1) DMA_TILE(2) DMA_TILE(3)

    f32x16 oacc[2][2];   // [strip][mt]
    #pragma unroll
    for (int s = 0; s < 2; ++s)
        #pragma unroll
        for (int mt = 0; mt < 2; ++mt)
            #pragma unroll
            for (int r = 0; r < 16; ++r) oacc[s][mt][r] = 0.f;
    f32x2 ds2[2];
    ds2[0][0]=0.f; ds2[0][1]=0.f; ds2[1][0]=0.f; ds2[1][1]=0.f;

    // persistent opaque zero C-operand
    f32x16 zacc;
    #pragma unroll
    for (int r = 0; r < 16; ++r) zacc[r] = 0.f;
    asm volatile("" : "+v"(zacc));

    unsigned int bsv[2][2][4];   // [strip][ksl][dword]

#define WAITVM_(N) asm volatile("s_waitcnt vmcnt(" #N ")" ::: "memory")
#define WAITVM(N) WAITVM_(N)

    // STEP: wait own tile-TT chunk (VM = newer DMAs in flight), barrier,
    // compute tile TT from slot TT&3, barrier, then (if ISSUE) DMA tile TT+4
    // into the freed slot.
#define STEP(TT, VM, ISSUE)                                                         \
    {                                                                               \
        WAITVM(VM);                                                                 \
        __builtin_amdgcn_s_barrier();                                               \
        asm volatile("" ::: "memory");                                              \
        __builtin_amdgcn_sched_barrier(0);                                          \
        const unsigned char* sb_ = smem + ((TT) & 3) * SLOT_BYTES;                  \
        const unsigned char* kp_ = sb_ + e * 4096 + (size_t)lane * 16;              \
        const unsigned char* vp_ = sb_ + 8192 + e * 4096 + (size_t)lane * 16;       \
        uint4 kf0 = *(const uint4*)(kp_);                                           \
        uint4 kf1 = *(const uint4*)(kp_ + 1024);                                    \
        uint4 kf2 = *(const uint4*)(kp_ + 2048);                                    \
        uint4 kf3 = *(const uint4*)(kp_ + 3072);                                    \
        uint4 vf0 = *(const uint4*)(vp_);                                           \
        uint4 vf1 = *(const uint4*)(vp_ + 1024);                                    \
        uint4 vf2 = *(const uint4*)(vp_ + 2048);                                    \
        uint4 vf3 = *(const uint4*)(vp_ + 3072);                                    \
        f32x16 acc0, acc1;                                                          \
        __builtin_amdgcn_s_setprio(1);                                              \
        {                                                                           \
            union { uint4 u; bf16x8 v; } kc;                                        \
            kc.u = kf0;                                                             \
            acc0 = __builtin_amdgcn_mfma_f32_32x32x16_bf16(kc.v, qfrag[0][0], zacc, 0, 0, 0); \
            acc1 = __builtin_amdgcn_mfma_f32_32x32x16_bf16(kc.v, qfrag[1][0], zacc, 0, 0, 0); \
            kc.u = kf1;                                                             \
            acc0 = __builtin_amdgcn_mfma_f32_32x32x16_bf16(kc.v, qfrag[0][1], acc0, 0, 0, 0); \
            acc1 = __builtin_amdgcn_mfma_f32_32x32x16_bf16(kc.v, qfrag[1][1], acc1, 0, 0, 0); \
            kc.u = kf2;                                                             \
            acc0 = __builtin_amdgcn_mfma_f32_32x32x16_bf16(kc.v, qfrag[0][2], acc0, 0, 0, 0); \
            acc1 = __builtin_amdgcn_mfma_f32_32x32x16_bf16(kc.v, qfrag[1][2], acc1, 0, 0, 0); \
            kc.u = kf3;                                                             \
            acc0 = __builtin_amdgcn_mfma_f32_32x32x16_bf16(kc.v, qfrag[0][3], acc0, 0, 0, 0); \
            acc1 = __builtin_amdgcn_mfma_f32_32x32x16_bf16(kc.v, qfrag[1][3], acc1, 0, 0, 0); \
        }                                                                           \
        __builtin_amdgcn_s_setprio(0);                                              \
        _Pragma("unroll")                                                           \
        for (int s = 0; s < 2; ++s) {                                               \
            unsigned int pk[4][2];                                                  \
            _Pragma("unroll")                                                       \
            for (int g = 0; g < 4; ++g) {                                           \
                f32x2 v01, v23;                                                     \
                v01[0] = (s ? acc1 : acc0)[4*g+0]; v01[1] = (s ? acc1 : acc0)[4*g+1]; \
                v23[0] = (s ? acc1 : acc0)[4*g+2]; v23[1] = (s ? acc1 : acc0)[4*g+3]; \
                v01 = v01 * v01; v23 = v23 * v23;                                   \
                ds2[s] += v01; ds2[s] += v23;                                       \
                pk[g][0] = pack2bf(v01[0], v01[1]);                                 \
                pk[g][1] = pack2bf(v23[0], v23[1]);                                 \
            }                                                                       \
            _Pragma("unroll")                                                       \
            for (int ksl = 0; ksl < 2; ++ksl) {                                     \
                unsigned int a0 = pk[2*ksl][0], b0 = pk[2*ksl+1][0];                \
                unsigned int a1 = pk[2*ksl][1], b1 = pk[2*ksl+1][1];                \
                pl32swap(a0, b0);                                                   \
                pl32swap(a1, b1);                                                   \
                bsv[s][ksl][0] = a0; bsv[s][ksl][1] = a1;                           \
                bsv[s][ksl][2] = b0; bsv[s][ksl][3] = b1;                           \
            }                                                                       \
        }                                                                           \
        __builtin_amdgcn_s_setprio(1);                                              \
        _Pragma("unroll")                                                           \
        for (int s = 0; s < 2; ++s) {                                               \
            _Pragma("unroll")                                                       \
            for (int ksl = 0; ksl < 2; ++ksl) {                                     \
                union { unsigned int d[4]; bf16x8 v; } bu;                          \
                bu.d[0] = bsv[s][ksl][0]; bu.d[1] = bsv[s][ksl][1];                 \
                bu.d[2] = bsv[s][ksl][2]; bu.d[3] = bsv[s][ksl][3];                 \
                union { uint4 u; bf16x8 v; } vv;                                    \
                vv.u = (ksl == 0 ? vf0 : vf2);                                      \
                oacc[s][0] = __builtin_amdgcn_mfma_f32_32x32x16_bf16(vv.v, bu.v, oacc[s][0], 0, 0, 0); \
                vv.u = (ksl == 0 ? vf1 : vf3);                                      \
                oacc[s][1] = __builtin_amdgcn_mfma_f32_32x32x16_bf16(vv.v, bu.v, oacc[s][1], 0, 0, 0); \
            }                                                                       \
        }                                                                           \
        __builtin_amdgcn_s_setprio(0);                                              \
        __builtin_amdgcn_s_barrier();                                               \
        asm volatile("" ::: "memory");                                              \
        if (ISSUE) DMA_TILE((TT) + 4)                                               \
    }

    for (int T = 0; T < NT - 4; ++T) {
        STEP(T, 12, 1);
    }
    STEP(NT - 4, 12, 0);
    STEP(NT - 3,  8, 0);
    STEP(NT - 2,  4, 0);
    STEP(NT - 1,  0, 0);
#undef STEP
#undef DMA_TILE
#undef WAITVM
#undef WAITVM_

    // ---- denominator partials (column i = l31, this wave's j-half, per strip) ----
    float wavetot[2];
    #pragma unroll
    for (int s = 0; s < 2; ++s) {
        float t = ds2[s][0] + ds2[s][1];
        wavetot[s] = t + __shfl_xor(t, 32);
    }

    // ---- epilogue: stash partials in (re-aliased) LDS, combine, store ----
    float* epb  = (float*)smem;                 // 8 regions x 32 x EPSTR
    float* dbuf = (float*)(smem + 69632);       // 256 floats
    #pragma unroll
    for (int s = 0; s < 2; ++s) {
        float* ep = epb + (size_t)(w * 2 + s) * (32 * EPSTR);
        #pragma unroll
        for (int mt = 0; mt < 2; ++mt) {
            #pragma unroll
            for (int g = 0; g < 4; ++g) {
                f32x4 vv;
                vv[0] = oacc[s][mt][4*g+0];
                vv[1] = oacc[s][mt][4*g+1];
                vv[2] = oacc[s][mt][4*g+2];
                vv[3] = oacc[s][mt][4*g+3];
                // O[i=l31][d = mt*32 + 8g + 4h + 0..3]
                *(f32x4*)&ep[l31 * EPSTR + mt * 32 + 8 * g + 4 * h] = vv;
            }
        }
        if (h == 0) dbuf[(w * 2 + s) * 32 + l31] = wavetot[s];
    }
    __syncthreads();

    // wave w handles output rows [32w, 32w+32): psrc = w>>1, ssrc = w&1
    const int psrc = w >> 1, ssrc = w & 1;
    const int r0 = (2 * psrc + 0) * 2 + ssrc;   // e=0 partial region
    const int r1 = (2 * psrc + 1) * 2 + ssrc;   // e=1 partial region
    const int lr = lane >> 1;
    const float den = dbuf[r0 * 32 + lr] + dbuf[r1 * 32 + lr];
    const float inv = 1.0f / fmaxf(den, 1e-4f);
    const float* ea = epb + (size_t)r0 * (32 * EPSTR) + lr * EPSTR;
    const float* eb = epb + (size_t)r1 * (32 * EPSTR) + lr * EPSTR;
    #pragma unroll
    for (int it = 0; it < 8; ++it) {
        int d0 = (lane & 1) * 32 + it * 4;
        f32x4 a = *(const f32x4*)&ea[d0];
        f32x4 b = *(const f32x4*)&eb[d0];
        f32x4 sm;
        sm[0] = (a[0] + b[0]) * inv;
        sm[1] = (a[1] + b[1]) * inv;
        sm[2] = (a[2] + b[2]) * inv;
        sm[3] = (a[3] + b[3]) * inv;
        *(f32x4*)&ob[(32 * w + lr) * DH + d0] = sm;
    }
}

// ---------------- fallback (self-contained, used if ws too small) ----------------
#define LSTR 72
__global__ __launch_bounds__(256, 2)
void poly_attn_fallback(const float* __restrict__ qg, const float* __restrict__ kg,
                        const float* __restrict__ vg, float* __restrict__ og)
{
    __shared__ unsigned short Qs[64 * LSTR];
    __shared__ unsigned short Ksl[64 * LSTR];
    __shared__ unsigned short Vt[64 * LSTR];
    __shared__ unsigned short Xsl[64 * LSTR];

    const int tid  = threadIdx.x;
    const int lane = tid & 63;
    const int w    = tid >> 6;
    const int c    = lane & 15;
    const int quad = lane >> 4;
    const int i0   = w * 16;

    const int bh = blockIdx.y;
    const int q0 = blockIdx.x * 64;

    const float* qb = qg + ((size_t)bh * S_LEN + q0) * DH;
    const float* kb = kg + (size_t)bh * S_LEN * DH;
    const float* vb = vg + (size_t)bh * S_LEN * DH;
    float*       ob = og + ((size_t)bh * S_LEN + q0) * DH;

    {
        const float4* qf4 = (const float4*)qb;
        #pragma unroll
        for (int r = 0; r < 4; ++r) {
            int idx = r * 256 + tid;
            int row = idx >> 4, c4 = idx & 15;
            float4 f = qf4[idx];
            ushort4 hh;
            hh.x = f2bf(f.x); hh.y = f2bf(f.y); hh.z = f2bf(f.z); hh.w = f2bf(f.w);
            *(ushort4*)&Qs[row * LSTR + c4 * 4] = hh;
        }
    }

    f32x4 oacc[4];
    #pragma unroll
    for (int t = 0; t < 4; ++t) { oacc[t][0]=0.f; oacc[t][1]=0.f; oacc[t][2]=0.f; oacc[t][3]=0.f; }
    float dsum[4] = {0.f, 0.f, 0.f, 0.f};

    for (int t0 = 0; t0 < S_LEN; t0 += 64) {
        __syncthreads();
        {
            const float4* kf4 = (const float4*)(kb + (size_t)t0 * DH);
            const float4* vf4 = (const float4*)(vb + (size_t)t0 * DH);
            #pragma unroll
            for (int r = 0; r < 4; ++r) {
                int idx = r * 256 + tid;
                int row = idx >> 4, c4 = idx & 15;
                float4 f = kf4[idx];
                ushort4 hh;
                hh.x = f2bf(f.x); hh.y = f2bf(f.y); hh.z = f2bf(f.z); hh.w = f2bf(f.w);
                *(ushort4*)&Ksl[row * LSTR + c4 * 4] = hh;
                float4 g = vf4[idx];
                int d0 = c4 * 4;
                Vt[(d0 + 0) * LSTR + row] = f2bf(g.x);
                Vt[(d0 + 1) * LSTR + row] = f2bf(g.y);
                Vt[(d0 + 2) * LSTR + row] = f2bf(g.z);
                Vt[(d0 + 3) * LSTR + row] = f2bf(g.w);
            }
        }
        __syncthreads();

        f32x4 xacc[4];
        #pragma unroll
        for (int t = 0; t < 4; ++t) { xacc[t][0]=0.f; xacc[t][1]=0.f; xacc[t][2]=0.f; xacc[t][3]=0.f; }
        #pragma unroll
        for (int k0 = 0; k0 < 64; k0 += 32) {
            bf16x8 af = *(const bf16x8*)&Qs[(i0 + c) * LSTR + k0 + quad * 8];
            #pragma unroll
            for (int tn = 0; tn < 4; ++tn) {
                bf16x8 bfg = *(const bf16x8*)&Ksl[(tn * 16 + c) * LSTR + k0 + quad * 8];
                xacc[tn] = __builtin_amdgcn_mfma_f32_16x16x32_bf16(af, bfg, xacc[tn], 0, 0, 0);
            }
        }
        #pragma unroll
        for (int tn = 0; tn < 4; ++tn)
            #pragma unroll
            for (int r = 0; r < 4; ++r) {
                float xv = xacc[tn][r];
                float xs = xv * xv;
                dsum[r] += xs;
                Xsl[(i0 + quad * 4 + r) * LSTR + tn * 16 + c] = f2bf(xs);
            }
        __syncthreads();

        #pragma unroll
        for (int k0 = 0; k0 < 64; k0 += 32) {
            bf16x8 af = *(const bf16x8*)&Xsl[(i0 + c) * LSTR + k0 + quad * 8];
            #pragma unroll
            for (int tn = 0; tn < 4; ++tn) {
                bf16x8 bfg = *(const bf16x8*)&Vt[(tn * 16 + c) * LSTR + k0 + quad * 8];
                oacc[tn] = __builtin_amdgcn_mfma_f32_16x16x32_bf16(af, bfg, oacc[tn], 0, 0, 0);
            }
        }
    }

    #pragma unroll
    for (int r = 0; r < 4; ++r) {
        float s = dsum[r];
        s += __shfl_xor(s, 1);
        s += __shfl_xor(s, 2);
        s += __shfl_xor(s, 4);
        s += __shfl_xor(s, 8);
        dsum[r] = 1.0f / fmaxf(s, 1e-4f);
    }
    #pragma unroll
    for (int tn = 0; tn < 4; ++tn)
        #pragma unroll
        for (int r = 0; r < 4; ++r)
            ob[(i0 + quad * 4 + r) * DH + tn * 16 + c] = oacc[tn][r] * dsum[r];
}

extern "C" void kernel_launch(void* const* d_in, const int* in_sizes, int n_in,
                              void* d_out, int out_size, void* d_ws, size_t ws_size,
                              hipStream_t stream) {
    (void)in_sizes; (void)n_in; (void)out_size;
    const float* q = (const float*)d_in[0];
    const float* k = (const float*)d_in[1];
    const float* v = (const float*)d_in[2];
    float* o = (float*)d_out;

    const size_t elems = (size_t)BH_N * PER_BH;              // 4,194,304
    const size_t need  = 2 * elems * sizeof(unsigned short); // 16.78 MB

    if (ws_size >= need) {
        unsigned short* kfo = (unsigned short*)d_ws;
        unsigned short* vfo = kfo + elems;
        prepass_kernel<<<dim3(NT, BH_N), 256, 0, stream>>>(k, v, kfo, vfo);
        poly_attn_main<<<dim3(BH_N * S_LEN / BQ), 256, 0, stream>>>(q, kfo, vfo, o);
    } else {
        poly_attn_fallback<<<dim3(S_LEN / 64, BH_N), 256, 0, stream>>>(q, k, v, o);
    }
}